// Round 12
// baseline (242.001 us; speedup 1.0000x reference)
//
#include <hip/hip_runtime.h>
#include <cmath>

#define B_ 8
#define C_ 256
#define N_ 4096
#define EPS_ 1e-8f

typedef _Float16 half8 __attribute__((ext_vector_type(8)));
typedef float f32x4 __attribute__((ext_vector_type(4)));
typedef unsigned short ushort8 __attribute__((ext_vector_type(8)));

__device__ __forceinline__ void gload_lds16(const void* g, void* l) {
  __builtin_amdgcn_global_load_lds((const __attribute__((address_space(1))) unsigned int*)g,
                                   (__attribute__((address_space(3))) unsigned int*)l, 16, 0, 0);
}

// Block-uniform need/valid recompute from partMax (64 partials per batch).
__device__ __forceinline__ float block_fore(const float* __restrict__ partMax, int b) {
  int l = threadIdx.x & 63;
  float v = partMax[(b << 6) + l];
#pragma unroll
  for (int d = 32; d; d >>= 1) v = fmaxf(v, __shfl_xor(v, d, 64));
  return v;
}

// ---------------- K_base: fused norms + valid-partial + base out + b=7 fp16 prep + cmp7 (b==8 row) ----
__global__ __launch_bounds__(512) void k_base(const float* __restrict__ x, const float* __restrict__ mask,
                                              float* __restrict__ fq, float* __restrict__ fs,
                                              float* __restrict__ out, float* __restrict__ partMax,
                                              int* __restrict__ mark,
                                              unsigned short* __restrict__ qhi, unsigned short* __restrict__ qlo,
                                              unsigned short* __restrict__ shi, unsigned short* __restrict__ slo,
                                              int* __restrict__ rowsrc, int* __restrict__ rowrank,
                                              int* __restrict__ colsrc, int* __restrict__ colmapG,
                                              int* __restrict__ cnt) {
  int b = blockIdx.y, n0 = blockIdx.x << 6;
  int t = threadIdx.x;            // 0..511
  if (b == B_) {
    // ---- compaction scan for b=7 (1 block of 512 threads, 8 elements each; stable order) ----
    if (blockIdx.x != 0) return;
    __shared__ int wtot[8], wbase[8], stot_s;
    int n0c = t << 3;
#pragma unroll
    for (int i = 0; i < 8; ++i) {
      rowsrc[t + (i << 9)] = 0;
      colsrc[t + (i << 9)] = 0;
      colmapG[t + (i << 9)] = 0x3fffffff;  // tail slots: huge but monotone col index
    }
    __syncthreads();
    int f[8]; int pk = 0;
#pragma unroll
    for (int i = 0; i < 8; ++i) {
      int m = (mask[(7 << 12) + n0c + i] != 0.f) ? 1 : 0;
      f[i] = m;
      pk += m ? 1 : (1 << 16);  // low 16: rows (m=1), high 16: cols (m=0)
    }
    int incl = pk;
#pragma unroll
    for (int d = 1; d < 64; d <<= 1) {
      int o = __shfl_up(incl, d, 64);
      if ((t & 63) >= d) incl += o;
    }
    if ((t & 63) == 63) wtot[t >> 6] = incl;
    __syncthreads();
    if (t < 8) {
      int s2 = 0;
      for (int i = 0; i < t; ++i) s2 += wtot[i];
      wbase[t] = s2;
      if (t == 7) stot_s = s2 + wtot[7];
    }
    __syncthreads();
    int excl = wbase[t >> 6] + incl - pk;   // packed exclusive prefix
    int rslot = excl & 0xffff, cslot = excl >> 16;
#pragma unroll
    for (int i = 0; i < 8; ++i) {
      int n2 = n0c + i;
      if (f[i]) { rowsrc[rslot] = n2; rowrank[n2] = rslot; ++rslot; }
      else      { rowrank[n2] = -1; colsrc[cslot] = n2; colmapG[cslot] = n2; ++cslot; }
    }
    __syncthreads();
    if (t == 0) {
      int tot = stot_s;
      int nr = tot & 0xffff;
      cnt[0] = nr;
      cnt[1] = tot >> 16;
      cnt[2] = (nr > 0) ? rowsrc[0] : 0x7fffffff;  // j0 = first inactive support col
      cnt[4] = 0;                                   // arrival counter for k_sim7 last-block
    }
    return;
  }
  int ln = t & 63, cg = t >> 6;   // 8 groups x 32 channels
  __shared__ float sred[512];
  __shared__ float s0[256];
  __shared__ float rss[8][64], rdp[8][64];
  __shared__ float scaleS[64], f64q[64], f64s[64];
  __shared__ float bcast[2];
  if (b == 0 && blockIdx.x == 0) {
#pragma unroll
    for (int i = 0; i < 8; ++i) mark[t + (i << 9)] = 0;
  }
  const size_t xbase = ((size_t)b * C_) << 12;
  float xc0 = 0.f;
  if (t < 256) xc0 = x[xbase + ((size_t)t << 12)];
  sred[t] = xc0 * xc0;
  __syncthreads();
  for (int s = 256; s; s >>= 1) { if (t < s) sred[t] += sred[t + s]; __syncthreads(); }
  if (t == 0) { bcast[0] = 1.f / (sqrtf(sred[0]) + EPS_); bcast[1] = mask[b << 12]; }
  __syncthreads();
  if (t < 256) s0[t] = xc0 * ((1.f - bcast[1]) * bcast[0]);
  __syncthreads();
  int n = n0 + ln;
  const float* xp = x + xbase + (((size_t)cg) << 17) + n;
  float xv[32];
  float ss = 0.f, dp = 0.f;
#pragma unroll
  for (int c = 0; c < 32; ++c) {
    float v = xp[(size_t)c << 12];
    xv[c] = v;
    ss += v * v;
    dp += v * s0[(cg << 5) + c];
  }
  rss[cg][ln] = ss; rdp[cg][ln] = dp;
  __syncthreads();
  if (t < 64) {
    float sst = 0.f, dpt = 0.f;
#pragma unroll
    for (int g = 0; g < 8; ++g) { sst += rss[g][t]; dpt += rdp[g][t]; }
    float inv = 1.f / (sqrtf(sst) + EPS_);
    float m = mask[(b << 12) + n0 + t];
    float fqv = m * inv;
    fq[(b << 12) + n0 + t] = fqv;
    fs[(b << 12) + n0 + t] = (1.f - m) * inv;
    scaleS[t] = (m != 0.f) ? inv : 1.f;
    f64q[t] = fqv * 64.0f;
    f64s[t] = (1.f - m) * inv * 64.0f;
    float val = dpt * fqv;  // masked rows -> exactly 0
#pragma unroll
    for (int d = 32; d; d >>= 1) val = fmaxf(val, __shfl_xor(val, d, 64));
    if (t == 0) partMax[(b << 6) + blockIdx.x] = val;
  }
  __syncthreads();
  float sc = scaleS[ln];
  float* op = out + xbase + (((size_t)cg) << 17) + n;
#pragma unroll
  for (int c = 0; c < 32; ++c) op[(size_t)c << 12] = xv[c] * sc;
  if (b == B_ - 1) {
    // fused prep: scaled (x64) fp16 hi/lo split, transposed, LINEAR layout (swizzle at staging)
    float fqn = f64q[ln], fsn = f64s[ln];
    size_t rowbase = ((size_t)n) << 8;  // 256 shorts per row
#pragma unroll
    for (int j = 0; j < 4; ++j) {
      ushort8 vqh, vql, vsh, vsl;
#pragma unroll
      for (int i = 0; i < 8; ++i) {
        float xvv = xv[j * 8 + i];
        float qv = xvv * fqn;
        _Float16 qh = (_Float16)qv;
        _Float16 ql = (_Float16)((qv - (float)qh) * 2048.0f);
        float sv = xvv * fsn;
        _Float16 sh = (_Float16)sv;
        _Float16 sl = (_Float16)((sv - (float)sh) * 2048.0f);
        vqh[i] = __builtin_bit_cast(unsigned short, qh);
        vql[i] = __builtin_bit_cast(unsigned short, ql);
        vsh[i] = __builtin_bit_cast(unsigned short, sh);
        vsl[i] = __builtin_bit_cast(unsigned short, sl);
      }
      size_t off = rowbase + ((size_t)cg << 5) + ((size_t)j << 3);
      *reinterpret_cast<ushort8*>(qhi + off) = vqh;
      *reinterpret_cast<ushort8*>(qlo + off) = vql;
      *reinterpret_cast<ushort8*>(shi + off) = vsh;
      *reinterpret_cast<ushort8*>(slo + off) = vsl;
    }
  }
}

// ---------------- K_sim7: compacted MFMA sim (8 waves/block) + last-block reduce + gated simL -----
__global__ __launch_bounds__(512, 2) void k_sim7(const unsigned short* __restrict__ qhi, const unsigned short* __restrict__ qlo,
                                                 const unsigned short* __restrict__ shi, const unsigned short* __restrict__ slo,
                                                 const int* __restrict__ rowsrc, const int* __restrict__ rowrank,
                                                 const int* __restrict__ colsrc, const int* __restrict__ colmapG,
                                                 int* __restrict__ cnt,
                                                 float* __restrict__ partV, int* __restrict__ partI,
                                                 const float* __restrict__ x, const float* __restrict__ mask,
                                                 const float* __restrict__ partMax,
                                                 const float* __restrict__ fq, const float* __restrict__ fs,
                                                 float* __restrict__ wv, int* __restrict__ idxv,
                                                 int* __restrict__ mark) {
  __shared__ __align__(16) unsigned short smem[2][16384];  // 2 x 32KB double buffer
  __shared__ int lastblk;
  int bid = blockIdx.x;
  int tid = threadIdx.x;

  if (bid < 1024) {
    int nrows = cnt[0], ncols = cnt[1];
    int mt = bid & 31, nt = bid >> 5;
    int active = !(((nt << 7) >= nrows) || ((mt << 7) >= ncols));
    if (active) {
      int w = tid >> 6, lane = tid & 63;
      int wy = w >> 2, wx = w & 3;           // 2 row-halves x 4 col-quarters
      int arr = w >> 1, shalf = w & 1;       // array 0..3 (qhi,qlo,shi,slo), seg half

      f32x4 acc_h[4][2], acc_c[4][2];
#pragma unroll
      for (int i = 0; i < 4; ++i)
#pragma unroll
        for (int j = 0; j < 2; ++j) {
          acc_h[i][j] = (f32x4){0.f, 0.f, 0.f, 0.f};
          acc_c[i][j] = (f32x4){0.f, 0.f, 0.f, 0.f};
        }

      const unsigned short* gsrc = (arr == 0) ? qhi : (arr == 1) ? qlo : (arr == 2) ? shi : slo;
      const int* srcmap = (arr < 2) ? rowsrc : colsrc;
      int n0 = ((arr < 2) ? nt : mt) << 7;
      int lrow = lane >> 2, lch = lane & 3;
      int chx = (lch ^ ((lrow >> 1) & 3)) << 3;   // slot-keyed chunk swizzle
      int s = lane >> 4, c16 = lane & 15;
      int srco[4];
#pragma unroll
      for (int s2 = 0; s2 < 4; ++s2) {
        int seg = (shalf << 2) + s2;
        srco[s2] = (srcmap[n0 + (seg << 4) + lrow] << 8) + chx;
      }

#define STAGE7(buf, kt)                                                                   \
  _Pragma("unroll")                                                                       \
  for (int s2 = 0; s2 < 4; ++s2) {                                                        \
    const unsigned short* g = gsrc + (size_t)(srco[s2] + ((kt) << 5));                    \
    gload_lds16(g, &smem[buf][(arr << 12) + ((((shalf << 2) + s2)) << 9)]);               \
  }

      STAGE7(0, 0);

      int cur = 0;
      for (int kt = 0; kt < 8; ++kt) {
        if (kt < 7) {
          STAGE7(cur ^ 1, kt + 1);
          asm volatile("s_waitcnt vmcnt(4)" ::: "memory");   // own cur-buffer loads retired
        } else {
          asm volatile("s_waitcnt vmcnt(0)" ::: "memory");
        }
        __builtin_amdgcn_s_barrier();
        __builtin_amdgcn_sched_barrier(0);
        const unsigned short* sm = &smem[cur][0];
        half8 ah[4], al[4], bh[2], bl[2];
#pragma unroll
        for (int f = 0; f < 4; ++f) {
          int ra = (wy << 6) + (f << 4) + c16;
          int oa = ra * 32 + ((s ^ ((ra >> 1) & 3)) << 3);
          ah[f] = *reinterpret_cast<const half8*>(&sm[oa]);
          al[f] = *reinterpret_cast<const half8*>(&sm[4096 + oa]);
        }
#pragma unroll
        for (int f = 0; f < 2; ++f) {
          int rb = (wx << 5) + (f << 4) + c16;
          int ob = rb * 32 + ((s ^ ((rb >> 1) & 3)) << 3);
          bh[f] = *reinterpret_cast<const half8*>(&sm[8192 + ob]);
          bl[f] = *reinterpret_cast<const half8*>(&sm[12288 + ob]);
        }
#pragma unroll
        for (int fi = 0; fi < 4; ++fi)
#pragma unroll
          for (int fj = 0; fj < 2; ++fj) {
            acc_h[fi][fj] = __builtin_amdgcn_mfma_f32_16x16x32_f16(ah[fi], bh[fj], acc_h[fi][fj], 0, 0, 0);
            acc_c[fi][fj] = __builtin_amdgcn_mfma_f32_16x16x32_f16(ah[fi], bl[fj], acc_c[fi][fj], 0, 0, 0);
            acc_c[fi][fj] = __builtin_amdgcn_mfma_f32_16x16x32_f16(al[fi], bh[fj], acc_c[fi][fj], 0, 0, 0);
          }
        asm volatile("s_waitcnt lgkmcnt(0)" ::: "memory");
        __builtin_amdgcn_s_barrier();
        __builtin_amdgcn_sched_barrier(0);
        cur ^= 1;
      }
#undef STAGE7
      int cg4[2], cok[2];
#pragma unroll
      for (int fj = 0; fj < 2; ++fj) {
        int slotg = (mt << 7) + (wx << 5) + (fj << 4) + c16;
        cg4[fj] = colmapG[slotg];
        cok[fj] = slotg < ncols;
      }
      float* redV = reinterpret_cast<float*>(&smem[0][0]);       // [128][4]
      int* redI = reinterpret_cast<int*>(&smem[0][1024]);        // [128][4]
      int g16 = lane >> 4;
#pragma unroll
      for (int fi = 0; fi < 4; ++fi)
#pragma unroll
        for (int r2 = 0; r2 < 4; ++r2) {
          float bv = -INFINITY; int bi = 0x7fffffff;
#pragma unroll
          for (int fj = 0; fj < 2; ++fj) {
            float v = cok[fj] ? (acc_h[fi][fj][r2] + acc_c[fi][fj][r2] * (1.0f / 2048.0f)) * (1.0f / 4096.0f)
                              : -INFINITY;
            int colg = cg4[fj];
            if (v > bv) { bv = v; bi = colg; }
          }
#pragma unroll
          for (int d = 1; d < 16; d <<= 1) {
            float ov = __shfl_xor(bv, d, 64);
            int oi = __shfl_xor(bi, d, 64);
            if (ov > bv || (ov == bv && oi < bi)) { bv = ov; bi = oi; }
          }
          if (c16 == 0) {
            int row = (wy << 6) + (fi << 4) + (g16 << 2) + r2;
            redV[row * 4 + wx] = bv;
            redI[row * 4 + wx] = bi;
          }
        }
      __syncthreads();
      if (tid < 128) {
        float bv = redV[tid * 4]; int bi = redI[tid * 4];
#pragma unroll
        for (int q = 1; q < 4; ++q) {   // wx ascending -> cols ascending
          float v = redV[tid * 4 + q]; int i = redI[tid * 4 + q];
          if (v > bv || (v == bv && i < bi)) { bv = v; bi = i; }
        }
        int n = (nt << 7) + tid;   // compact slot row
        partV[(((size_t)n) << 5) + mt] = bv;
        partI[(((size_t)n) << 5) + mt] = bi;
      }
    }
    // ---- arrival: last of the 1024 sim blocks performs the de-compact reduce + mark ----
    __threadfence();
    if (tid == 0) {
      int old = atomicAdd(&cnt[4], 1);
      lastblk = (old == 1023) ? 1 : 0;
    }
    __syncthreads();
    if (lastblk) {
      __threadfence();
      int ncols2 = cnt[1], j0 = cnt[2];
      int mtmax = (ncols2 + 127) >> 7;
#pragma unroll
      for (int rr2 = 0; rr2 < 8; ++rr2) {
        int n = (rr2 << 9) + tid;   // 8 x 512 = 4096 rows
        int rk = rowrank[n];
        float bv; int bi;
        if (rk < 0) {
          bv = 0.f; bi = 0;
        } else {
          bv = -INFINITY; bi = 0x7fffffff;
          for (int mt2 = 0; mt2 < mtmax; ++mt2) {
            float v = partV[(((size_t)rk) << 5) + mt2];
            int i = partI[(((size_t)rk) << 5) + mt2];
            if (v > bv || (v == bv && i < bi)) { bv = v; bi = i; }
          }
          if (j0 < N_) {
            if (0.f > bv) { bv = 0.f; bi = j0; }
            else if (0.f == bv && j0 < bi) bi = j0;
          }
        }
        wv[((B_ - 1) << 12) + n] = bv;
        idxv[((B_ - 1) << 12) + n] = bi;
        mark[bi] = 1;  // benign same-value race
      }
    }
    return;
  }

  // ---- legacy fp32 sim for b<7, full-row argmax (gated; ~never runs on this data) ----
  int rr = bid - 1024;           // 0..447
  int b = rr >> 6;
  float fore = block_fore(partMax, b);
  if (!(fore > 0.5f) || mask[b << 12] == 0.f) return;  // need==0
  if (tid >= 256) return;        // waves 4..7 exit before any barrier
  int n0 = (rr & 63) << 6;
  int tx = tid & 15, ty = tid >> 4;
  int lk = ty, ln4 = tx << 2;
  // alias legacy LDS into smem (uses ~22KB of 64KB)
  float* As = reinterpret_cast<float*>(&smem[0][0]);      // [16][68]
  float* Bs = As + 1088;                                   // [16][68]
  float* fqs = Bs + 1088;                                  // [64]
  float* fss = fqs + 64;                                   // [64]
  float* rv = fss + 64;                                    // [64][17]
  int* ri = reinterpret_cast<int*>(rv + 1088);             // [64][17]

  if (tid < 64) fqs[tid] = fq[(b << 12) + n0 + tid];

  float bestv[4]; int besti[4];
#pragma unroll
  for (int i = 0; i < 4; ++i) { bestv[i] = -INFINITY; besti[i] = 0; }

  const size_t xb = ((size_t)b * C_) << 12;

  for (int m0 = 0; m0 < N_; m0 += 64) {
    if (tid < 64) fss[tid] = fs[(b << 12) + m0 + tid];
    float cacc[4][4];
#pragma unroll
    for (int i = 0; i < 4; ++i)
#pragma unroll
      for (int j = 0; j < 4; ++j) cacc[i][j] = 0.f;
    __syncthreads();
    for (int kt = 0; kt < C_; kt += 16) {
      float4 va = *reinterpret_cast<const float4*>(x + xb + ((size_t)(kt + lk) << 12) + n0 + ln4);
      float4 vb = *reinterpret_cast<const float4*>(x + xb + ((size_t)(kt + lk) << 12) + m0 + ln4);
      va.x *= fqs[ln4]; va.y *= fqs[ln4 + 1]; va.z *= fqs[ln4 + 2]; va.w *= fqs[ln4 + 3];
      vb.x *= fss[ln4]; vb.y *= fss[ln4 + 1]; vb.z *= fss[ln4 + 2]; vb.w *= fss[ln4 + 3];
      *reinterpret_cast<float4*>(&As[lk * 68 + ln4]) = va;
      *reinterpret_cast<float4*>(&Bs[lk * 68 + ln4]) = vb;
      __syncthreads();
#pragma unroll
      for (int k = 0; k < 16; ++k) {
        float a0 = As[k * 68 + (ty << 2) + 0], a1 = As[k * 68 + (ty << 2) + 1];
        float a2 = As[k * 68 + (ty << 2) + 2], a3 = As[k * 68 + (ty << 2) + 3];
        float b0 = Bs[k * 68 + (tx << 2) + 0], b1 = Bs[k * 68 + (tx << 2) + 1];
        float b2 = Bs[k * 68 + (tx << 2) + 2], b3 = Bs[k * 68 + (tx << 2) + 3];
        cacc[0][0] += a0 * b0; cacc[0][1] += a0 * b1; cacc[0][2] += a0 * b2; cacc[0][3] += a0 * b3;
        cacc[1][0] += a1 * b0; cacc[1][1] += a1 * b1; cacc[1][2] += a1 * b2; cacc[1][3] += a1 * b3;
        cacc[2][0] += a2 * b0; cacc[2][1] += a2 * b1; cacc[2][2] += a2 * b2; cacc[2][3] += a2 * b3;
        cacc[3][0] += a3 * b0; cacc[3][1] += a3 * b1; cacc[3][2] += a3 * b2; cacc[3][3] += a3 * b3;
      }
      __syncthreads();
    }
#pragma unroll
    for (int j = 0; j < 4; ++j) {
      int col = m0 + (tx << 2) + j;
#pragma unroll
      for (int i = 0; i < 4; ++i) {
        float v = cacc[i][j];
        if (v > bestv[i]) { bestv[i] = v; besti[i] = col; }
      }
    }
  }
#pragma unroll
  for (int i = 0; i < 4; ++i) { rv[((ty << 2) + i) * 17 + tx] = bestv[i]; ri[((ty << 2) + i) * 17 + tx] = besti[i]; }
  __syncthreads();
  if (tid < 64) {
    float bv = rv[tid * 17]; int bi = ri[tid * 17];
#pragma unroll
    for (int t2 = 1; t2 < 16; ++t2) {
      float v = rv[tid * 17 + t2]; int ii = ri[tid * 17 + t2];
      if (v > bv || (v == bv && ii < bi)) { bv = v; bi = ii; }
    }
    wv[(b << 12) + n0 + tid] = bv;
    idxv[(b << 12) + n0 + tid] = bi;
  }
}

// ---------------- K_epi: attmap upsample (bid<1024) + gated hybrid conv (bid>=1024) ----------------
__global__ __launch_bounds__(256) void k_epi(const int* __restrict__ mark, float* __restrict__ att,
                                             const float* __restrict__ x, const float* __restrict__ mask,
                                             const float* __restrict__ partMax,
                                             const float* __restrict__ fq, const float* __restrict__ fs,
                                             const float* __restrict__ Wc, const float* __restrict__ bc,
                                             const int* __restrict__ idxv, const float* __restrict__ wv,
                                             float* __restrict__ out) {
  int bid = blockIdx.x;
  int tid = threadIdx.x;
  if (bid < 1024) {
    int id = bid * 256 + tid;
    int x8 = (id & 63) << 3;
    int y = (id >> 6) & 511;
    int b = id >> 15;
    float v = mark[((y >> 3) << 6) + (x8 >> 3)] ? 1.f : 0.f;
    float4 vv = make_float4(v, v, v, v);
    float* p = att + (((size_t)b) << 18) + (y << 9) + x8;
    *reinterpret_cast<float4*>(p) = vv;
    *reinterpret_cast<float4*>(p + 4) = vv;
    return;
  }
  // ---- gated 1x1-conv hybrid overwrite (inline valid + softmax scalars) ----
  int rr = bid - 1024;      // 0..127
  int b = rr >> 4;
  int bx = rr & 15;
  float fore = block_fore(partMax, b);
  if (!(fore > 0.5f) || mask[b << 12] == 0.f) return;  // valid==0
  __shared__ float red[256];
  float mx = -INFINITY;
  for (int n = tid; n < N_; n += 256) mx = fmaxf(mx, wv[(b << 12) + n]);
  red[tid] = mx; __syncthreads();
  for (int s = 128; s; s >>= 1) { if (tid < s) red[tid] = fmaxf(red[tid], red[tid + s]); __syncthreads(); }
  mx = red[0]; __syncthreads();
  float sm = 0.f;
  for (int n = tid; n < N_; n += 256) sm += expf(wv[(b << 12) + n] - mx);
  red[tid] = sm; __syncthreads();
  for (int s = 128; s; s >>= 1) { if (tid < s) red[tid] += red[tid + s]; __syncthreads(); }
  float den = red[0];

  int n = bx * 256 + tid;
  int bn = (b << 12) + n;
  float mn = mask[bn];
  if (mn == 0.f) return;
  int j = idxv[bn];
  float w = expf(wv[bn] - mx) / den;
  float fsj = fs[(b << 12) + j];
  float fqn = fq[bn];
  const float* xb = x + (((size_t)b * C_) << 12);
  for (int o = 0; o < C_; ++o) {
    const float* wr = Wc + o * 2 * C_;
    float a1 = 0.f, a2 = 0.f;
    for (int i = 0; i < C_; ++i) {
      a1 += wr[i] * xb[((size_t)i << 12) + j];
      a2 += wr[C_ + i] * xb[((size_t)i << 12) + n];
    }
    out[((size_t)(b * C_ + o) << 12) + n] = bc[o] + a1 * (fsj * w) + a2 * fqn;
  }
}

extern "C" void kernel_launch(void* const* d_in, const int* in_sizes, int n_in,
                              void* d_out, int out_size, void* d_ws, size_t ws_size,
                              hipStream_t stream) {
  const float* x = (const float*)d_in[0];
  const float* mask = (const float*)d_in[1];
  const float* Wc = (const float*)d_in[2];
  const float* bc = (const float*)d_in[3];
  float* out = (float*)d_out;
  float* att = out + (size_t)B_ * C_ * N_;

  float* wsf = (float*)d_ws;
  float* fq = wsf;                          // 32768
  float* fs = wsf + 32768;                  // 32768
  float* wv = wsf + 65536;                  // 32768
  int* idxv = (int*)(wsf + 98304);          // 32768 -> ends 131072
  int* rowsrc = (int*)(wsf + 131072);       // 4096
  int* rowrank = (int*)(wsf + 135168);      // 4096
  int* colsrc = (int*)(wsf + 139264);       // 4096
  int* colmapG = (int*)(wsf + 143360);      // 4096
  int* cnt = (int*)(wsf + 147456);          // 8 -> ends 147464
  int* mark = (int*)(wsf + 655392);         // 4096 -> ends 659488
  float* partMax = wsf + 659488;            // 512 -> ends 660000
  float* p7V = wsf + 660000;                // 131072 -> ends 791072
  int* p7I = (int*)(wsf + 791072);          // 131072 -> ends 922144
  unsigned short* qhi = (unsigned short*)(wsf + 922144);   // 524288 floats (2MB) each
  unsigned short* qlo = (unsigned short*)(wsf + 1446432);
  unsigned short* shi = (unsigned short*)(wsf + 1970720);
  unsigned short* slo = (unsigned short*)(wsf + 2495008);  // end: 3019296 floats (~11.5MB)

  k_base<<<dim3(64, B_ + 1), 512, 0, stream>>>(x, mask, fq, fs, out, partMax, mark,
                                               qhi, qlo, shi, slo,
                                               rowsrc, rowrank, colsrc, colmapG, cnt);
  k_sim7<<<1472, 512, 0, stream>>>(qhi, qlo, shi, slo, rowsrc, rowrank, colsrc, colmapG, cnt,
                                   p7V, p7I, x, mask, partMax, fq, fs, wv, idxv, mark);
  k_epi<<<1152, 256, 0, stream>>>(mark, att, x, mask, partMax, fq, fs, Wc, bc, idxv, wv, out);
}

// Round 13
// 62.380 us; speedup vs baseline: 3.8795x; 3.8795x over previous
//
#include <hip/hip_runtime.h>
#include <cmath>

#define B_ 8
#define C_ 256
#define N_ 4096
#define EPS_ 1e-8f

typedef _Float16 half8 __attribute__((ext_vector_type(8)));
typedef float f32x4 __attribute__((ext_vector_type(4)));
typedef unsigned short ushort8 __attribute__((ext_vector_type(8)));

__device__ __forceinline__ void gload_lds16(const void* g, void* l) {
  __builtin_amdgcn_global_load_lds((const __attribute__((address_space(1))) unsigned int*)g,
                                   (__attribute__((address_space(3))) unsigned int*)l, 16, 0, 0);
}

// Block-uniform need/valid recompute from partMax (64 partials per batch).
__device__ __forceinline__ float block_fore(const float* __restrict__ partMax, int b) {
  int l = threadIdx.x & 63;
  float v = partMax[(b << 6) + l];
#pragma unroll
  for (int d = 32; d; d >>= 1) v = fmaxf(v, __shfl_xor(v, d, 64));
  return v;
}

// ---------------- K_base: fused norms + valid-partial + base out + b=7 fp16 prep + cmp7 (b==8 row) ----
__global__ __launch_bounds__(512) void k_base(const float* __restrict__ x, const float* __restrict__ mask,
                                              float* __restrict__ fq, float* __restrict__ fs,
                                              float* __restrict__ out, float* __restrict__ partMax,
                                              int* __restrict__ mark,
                                              unsigned short* __restrict__ qhi, unsigned short* __restrict__ qlo,
                                              unsigned short* __restrict__ shi, unsigned short* __restrict__ slo,
                                              int* __restrict__ rowsrc, int* __restrict__ rowrank,
                                              int* __restrict__ colsrc, int* __restrict__ colmapG,
                                              int* __restrict__ cnt) {
  int b = blockIdx.y, n0 = blockIdx.x << 6;
  int t = threadIdx.x;            // 0..511
  if (b == B_) {
    // ---- compaction scan for b=7 (1 block of 512 threads, 8 elements each; stable order) ----
    if (blockIdx.x != 0) return;
    __shared__ int wtot[8], wbase[8], stot_s;
    int n0c = t << 3;
#pragma unroll
    for (int i = 0; i < 8; ++i) {
      rowsrc[t + (i << 9)] = 0;
      colsrc[t + (i << 9)] = 0;
      colmapG[t + (i << 9)] = 0x3fffffff;  // tail slots: huge but monotone col index
    }
    __syncthreads();
    int f[8]; int pk = 0;
#pragma unroll
    for (int i = 0; i < 8; ++i) {
      int m = (mask[(7 << 12) + n0c + i] != 0.f) ? 1 : 0;
      f[i] = m;
      pk += m ? 1 : (1 << 16);  // low 16: rows (m=1), high 16: cols (m=0)
    }
    int incl = pk;
#pragma unroll
    for (int d = 1; d < 64; d <<= 1) {
      int o = __shfl_up(incl, d, 64);
      if ((t & 63) >= d) incl += o;
    }
    if ((t & 63) == 63) wtot[t >> 6] = incl;
    __syncthreads();
    if (t < 8) {
      int s2 = 0;
      for (int i = 0; i < t; ++i) s2 += wtot[i];
      wbase[t] = s2;
      if (t == 7) stot_s = s2 + wtot[7];
    }
    __syncthreads();
    int excl = wbase[t >> 6] + incl - pk;   // packed exclusive prefix
    int rslot = excl & 0xffff, cslot = excl >> 16;
#pragma unroll
    for (int i = 0; i < 8; ++i) {
      int n2 = n0c + i;
      if (f[i]) { rowsrc[rslot] = n2; rowrank[n2] = rslot; ++rslot; }
      else      { rowrank[n2] = -1; colsrc[cslot] = n2; colmapG[cslot] = n2; ++cslot; }
    }
    __syncthreads();
    if (t == 0) {
      int tot = stot_s;
      int nr = tot & 0xffff;
      cnt[0] = nr;
      cnt[1] = tot >> 16;
      cnt[2] = (nr > 0) ? rowsrc[0] : 0x7fffffff;  // j0 = first inactive support col
    }
    return;
  }
  int ln = t & 63, cg = t >> 6;   // 8 groups x 32 channels
  __shared__ float sred[512];
  __shared__ float s0[256];
  __shared__ float rss[8][64], rdp[8][64];
  __shared__ float scaleS[64], f64q[64], f64s[64];
  __shared__ float bcast[2];
  if (b == 0 && blockIdx.x == 0) {
#pragma unroll
    for (int i = 0; i < 8; ++i) mark[t + (i << 9)] = 0;
  }
  const size_t xbase = ((size_t)b * C_) << 12;
  float xc0 = 0.f;
  if (t < 256) xc0 = x[xbase + ((size_t)t << 12)];
  sred[t] = xc0 * xc0;
  __syncthreads();
  for (int s = 256; s; s >>= 1) { if (t < s) sred[t] += sred[t + s]; __syncthreads(); }
  if (t == 0) { bcast[0] = 1.f / (sqrtf(sred[0]) + EPS_); bcast[1] = mask[b << 12]; }
  __syncthreads();
  if (t < 256) s0[t] = xc0 * ((1.f - bcast[1]) * bcast[0]);
  __syncthreads();
  int n = n0 + ln;
  const float* xp = x + xbase + (((size_t)cg) << 17) + n;
  float xv[32];
  float ss = 0.f, dp = 0.f;
#pragma unroll
  for (int c = 0; c < 32; ++c) {
    float v = xp[(size_t)c << 12];
    xv[c] = v;
    ss += v * v;
    dp += v * s0[(cg << 5) + c];
  }
  rss[cg][ln] = ss; rdp[cg][ln] = dp;
  __syncthreads();
  if (t < 64) {
    float sst = 0.f, dpt = 0.f;
#pragma unroll
    for (int g = 0; g < 8; ++g) { sst += rss[g][t]; dpt += rdp[g][t]; }
    float inv = 1.f / (sqrtf(sst) + EPS_);
    float m = mask[(b << 12) + n0 + t];
    float fqv = m * inv;
    fq[(b << 12) + n0 + t] = fqv;
    fs[(b << 12) + n0 + t] = (1.f - m) * inv;
    scaleS[t] = (m != 0.f) ? inv : 1.f;
    f64q[t] = fqv * 64.0f;
    f64s[t] = (1.f - m) * inv * 64.0f;
    float val = dpt * fqv;  // masked rows -> exactly 0
#pragma unroll
    for (int d = 32; d; d >>= 1) val = fmaxf(val, __shfl_xor(val, d, 64));
    if (t == 0) partMax[(b << 6) + blockIdx.x] = val;
  }
  __syncthreads();
  float sc = scaleS[ln];
  float* op = out + xbase + (((size_t)cg) << 17) + n;
#pragma unroll
  for (int c = 0; c < 32; ++c) op[(size_t)c << 12] = xv[c] * sc;
  if (b == B_ - 1) {
    // fused prep: scaled (x64) fp16 hi/lo split, transposed, LINEAR layout (swizzle at staging)
    float fqn = f64q[ln], fsn = f64s[ln];
    size_t rowbase = ((size_t)n) << 8;  // 256 shorts per row
#pragma unroll
    for (int j = 0; j < 4; ++j) {
      ushort8 vqh, vql, vsh, vsl;
#pragma unroll
      for (int i = 0; i < 8; ++i) {
        float xvv = xv[j * 8 + i];
        float qv = xvv * fqn;
        _Float16 qh = (_Float16)qv;
        _Float16 ql = (_Float16)((qv - (float)qh) * 2048.0f);
        float sv = xvv * fsn;
        _Float16 sh = (_Float16)sv;
        _Float16 sl = (_Float16)((sv - (float)sh) * 2048.0f);
        vqh[i] = __builtin_bit_cast(unsigned short, qh);
        vql[i] = __builtin_bit_cast(unsigned short, ql);
        vsh[i] = __builtin_bit_cast(unsigned short, sh);
        vsl[i] = __builtin_bit_cast(unsigned short, sl);
      }
      size_t off = rowbase + ((size_t)cg << 5) + ((size_t)j << 3);
      *reinterpret_cast<ushort8*>(qhi + off) = vqh;
      *reinterpret_cast<ushort8*>(qlo + off) = vql;
      *reinterpret_cast<ushort8*>(shi + off) = vsh;
      *reinterpret_cast<ushort8*>(slo + off) = vsl;
    }
  }
}

// ---------------- K_sim7: compacted MFMA sim + row argmax for b=7 ----------------
__global__ __launch_bounds__(256, 2) void k_sim7(const unsigned short* __restrict__ qhi, const unsigned short* __restrict__ qlo,
                                                 const unsigned short* __restrict__ shi, const unsigned short* __restrict__ slo,
                                                 const int* __restrict__ rowsrc, const int* __restrict__ colsrc,
                                                 const int* __restrict__ colmapG, const int* __restrict__ cnt,
                                                 float* __restrict__ partV, int* __restrict__ partI) {
  int nrows = cnt[0], ncols = cnt[1];
  int bid = blockIdx.x;
  int mt = bid & 31, nt = bid >> 5;
  if ((nt << 7) >= nrows || (mt << 7) >= ncols) return;  // data-dependent tile cull
  int tid = threadIdx.x;
  int w = tid >> 6, lane = tid & 63;
  int wy = w >> 1, wx = w & 1;
  __shared__ __align__(16) unsigned short smem[2][16384];  // 2 x 32KB double buffer

  f32x4 acc_h[4][4], acc_c[4][4];
#pragma unroll
  for (int i = 0; i < 4; ++i)
#pragma unroll
    for (int j = 0; j < 4; ++j) {
      acc_h[i][j] = (f32x4){0.f, 0.f, 0.f, 0.f};
      acc_c[i][j] = (f32x4){0.f, 0.f, 0.f, 0.f};
    }

  const unsigned short* gsrc = (w == 0) ? qhi : (w == 1) ? qlo : (w == 2) ? shi : slo;
  const int* srcmap = (w < 2) ? rowsrc : colsrc;
  int n0 = ((w < 2) ? nt : mt) << 7;
  int lrow = lane >> 2, lch = lane & 3;
  int chx = (lch ^ ((lrow >> 1) & 3)) << 3;   // slot-keyed chunk swizzle
  int s = lane >> 4, c16 = lane & 15;
  int srco[8];
#pragma unroll
  for (int seg = 0; seg < 8; ++seg)
    srco[seg] = (srcmap[n0 + (seg << 4) + lrow] << 8) + chx;

#define STAGE7(buf, kt)                                                                \
  _Pragma("unroll")                                                                    \
  for (int seg = 0; seg < 8; ++seg) {                                                  \
    const unsigned short* g = gsrc + (size_t)(srco[seg] + ((kt) << 5));                \
    gload_lds16(g, &smem[buf][(w << 12) + (seg << 9)]);                                \
  }

  STAGE7(0, 0);

  int cur = 0;
  for (int kt = 0; kt < 8; ++kt) {
    if (kt < 7) {
      STAGE7(cur ^ 1, kt + 1);
      asm volatile("s_waitcnt vmcnt(8)" ::: "memory");
    } else {
      asm volatile("s_waitcnt vmcnt(0)" ::: "memory");
    }
    __builtin_amdgcn_s_barrier();
    __builtin_amdgcn_sched_barrier(0);
    const unsigned short* sm = &smem[cur][0];
    half8 ah[4], al[4], bh[4], bl[4];
#pragma unroll
    for (int f = 0; f < 4; ++f) {
      int ra = (wy << 6) + (f << 4) + c16;
      int oa = ra * 32 + ((s ^ ((ra >> 1) & 3)) << 3);
      ah[f] = *reinterpret_cast<const half8*>(&sm[oa]);
      al[f] = *reinterpret_cast<const half8*>(&sm[4096 + oa]);
      int rb = (wx << 6) + (f << 4) + c16;
      int ob = rb * 32 + ((s ^ ((rb >> 1) & 3)) << 3);
      bh[f] = *reinterpret_cast<const half8*>(&sm[8192 + ob]);
      bl[f] = *reinterpret_cast<const half8*>(&sm[12288 + ob]);
    }
#pragma unroll
    for (int fi = 0; fi < 4; ++fi)
#pragma unroll
      for (int fj = 0; fj < 4; ++fj) {
        acc_h[fi][fj] = __builtin_amdgcn_mfma_f32_16x16x32_f16(ah[fi], bh[fj], acc_h[fi][fj], 0, 0, 0);
        acc_c[fi][fj] = __builtin_amdgcn_mfma_f32_16x16x32_f16(ah[fi], bl[fj], acc_c[fi][fj], 0, 0, 0);
        acc_c[fi][fj] = __builtin_amdgcn_mfma_f32_16x16x32_f16(al[fi], bh[fj], acc_c[fi][fj], 0, 0, 0);
      }
    asm volatile("s_waitcnt lgkmcnt(0)" ::: "memory");
    __builtin_amdgcn_s_barrier();
    __builtin_amdgcn_sched_barrier(0);
    cur ^= 1;
  }
#undef STAGE7
  int cg4[4], cok[4];
#pragma unroll
  for (int fj = 0; fj < 4; ++fj) {
    int slotg = (mt << 7) + (wx << 6) + (fj << 4) + c16;
    cg4[fj] = colmapG[slotg];
    cok[fj] = slotg < ncols;
  }
  float* redV = reinterpret_cast<float*>(&smem[0][0]);       // [128][2]
  int* redI = reinterpret_cast<int*>(&smem[0][512]);         // [128][2]
  int g16 = lane >> 4;
#pragma unroll
  for (int fi = 0; fi < 4; ++fi)
#pragma unroll
    for (int r2 = 0; r2 < 4; ++r2) {
      float bv = -INFINITY; int bi = 0x7fffffff;
#pragma unroll
      for (int fj = 0; fj < 4; ++fj) {
        float v = cok[fj] ? (acc_h[fi][fj][r2] + acc_c[fi][fj][r2] * (1.0f / 2048.0f)) * (1.0f / 4096.0f)
                          : -INFINITY;
        int colg = cg4[fj];
        if (v > bv) { bv = v; bi = colg; }
      }
#pragma unroll
      for (int d = 1; d < 16; d <<= 1) {
        float ov = __shfl_xor(bv, d, 64);
        int oi = __shfl_xor(bi, d, 64);
        if (ov > bv || (ov == bv && oi < bi)) { bv = ov; bi = oi; }
      }
      if (c16 == 0) {
        int row = (wy << 6) + (fi << 4) + (g16 << 2) + r2;
        redV[row * 2 + wx] = bv;
        redI[row * 2 + wx] = bi;
      }
    }
  __syncthreads();
  if (tid < 128) {
    float v0 = redV[tid * 2], v1 = redV[tid * 2 + 1];
    int i0 = redI[tid * 2], i1 = redI[tid * 2 + 1];
    if (v1 > v0 || (v1 == v0 && i1 < i0)) { v0 = v1; i0 = i1; }
    int n = (nt << 7) + tid;   // compact slot row
    partV[(((size_t)n) << 5) + mt] = v0;
    partI[(((size_t)n) << 5) + mt] = i0;
  }
}

// ---------------- K_mid: red7m (bid<16) + legacy simL (bid>=16, gated ~never runs) ----------------
__global__ __launch_bounds__(256) void k_mid(const float* __restrict__ x, const float* __restrict__ mask,
                                             const float* __restrict__ partMax,
                                             const float* __restrict__ fq, const float* __restrict__ fs,
                                             const float* __restrict__ p7V, const int* __restrict__ p7I,
                                             const int* __restrict__ rowrank, const int* __restrict__ cnt,
                                             float* __restrict__ wv, int* __restrict__ idxv,
                                             int* __restrict__ mark) {
  int bid = blockIdx.x;
  int tid = threadIdx.x;
  if (bid < 16) {
    // ---- de-compact reduce for b=7 + inactive-col candidate + mark ----
    int n = bid * 256 + tid;   // orig row
    int ncols = cnt[1], j0 = cnt[2];
    int rk = rowrank[n];
    float bv; int bi;
    if (rk < 0) {
      bv = 0.f; bi = 0;
    } else {
      bv = -INFINITY; bi = 0x7fffffff;
      int mtmax = (ncols + 127) >> 7;
      for (int mt = 0; mt < mtmax; ++mt) {
        float v = p7V[(((size_t)rk) << 5) + mt];
        int i = p7I[(((size_t)rk) << 5) + mt];
        if (v > bv || (v == bv && i < bi)) { bv = v; bi = i; }
      }
      if (j0 < N_) {
        if (0.f > bv) { bv = 0.f; bi = j0; }
        else if (0.f == bv && j0 < bi) bi = j0;
      }
    }
    wv[((B_ - 1) << 12) + n] = bv;
    idxv[((B_ - 1) << 12) + n] = bi;
    mark[bi] = 1;  // benign same-value race
    return;
  }
  // ---- legacy fp32 sim for b<7, full-row argmax ----
  int rr = bid - 16;
  int b = rr >> 6;
  float fore = block_fore(partMax, b);
  if (!(fore > 0.5f) || mask[b << 12] == 0.f) return;  // need==0 for b<7
  int n0 = (rr & 63) << 6;
  int tx = tid & 15, ty = tid >> 4;
  int lk = ty, ln4 = tx << 2;

  __shared__ float As[16][68];
  __shared__ float Bs[16][68];
  __shared__ float fqs[64], fss[64];
  __shared__ float rv[64][17];
  __shared__ int ri[64][17];

  if (tid < 64) fqs[tid] = fq[(b << 12) + n0 + tid];

  float bestv[4]; int besti[4];
#pragma unroll
  for (int i = 0; i < 4; ++i) { bestv[i] = -INFINITY; besti[i] = 0; }

  const size_t xb = ((size_t)b * C_) << 12;

  for (int m0 = 0; m0 < N_; m0 += 64) {
    if (tid < 64) fss[tid] = fs[(b << 12) + m0 + tid];
    float cacc[4][4];
#pragma unroll
    for (int i = 0; i < 4; ++i)
#pragma unroll
      for (int j = 0; j < 4; ++j) cacc[i][j] = 0.f;
    __syncthreads();
    for (int kt = 0; kt < C_; kt += 16) {
      float4 va = *reinterpret_cast<const float4*>(x + xb + ((size_t)(kt + lk) << 12) + n0 + ln4);
      float4 vb = *reinterpret_cast<const float4*>(x + xb + ((size_t)(kt + lk) << 12) + m0 + ln4);
      va.x *= fqs[ln4]; va.y *= fqs[ln4 + 1]; va.z *= fqs[ln4 + 2]; va.w *= fqs[ln4 + 3];
      vb.x *= fss[ln4]; vb.y *= fss[ln4 + 1]; vb.z *= fss[ln4 + 2]; vb.w *= fss[ln4 + 3];
      *reinterpret_cast<float4*>(&As[lk][ln4]) = va;
      *reinterpret_cast<float4*>(&Bs[lk][ln4]) = vb;
      __syncthreads();
#pragma unroll
      for (int k = 0; k < 16; ++k) {
        float a0 = As[k][(ty << 2) + 0], a1 = As[k][(ty << 2) + 1], a2 = As[k][(ty << 2) + 2], a3 = As[k][(ty << 2) + 3];
        float b0 = Bs[k][(tx << 2) + 0], b1 = Bs[k][(tx << 2) + 1], b2 = Bs[k][(tx << 2) + 2], b3 = Bs[k][(tx << 2) + 3];
        cacc[0][0] += a0 * b0; cacc[0][1] += a0 * b1; cacc[0][2] += a0 * b2; cacc[0][3] += a0 * b3;
        cacc[1][0] += a1 * b0; cacc[1][1] += a1 * b1; cacc[1][2] += a1 * b2; cacc[1][3] += a1 * b3;
        cacc[2][0] += a2 * b0; cacc[2][1] += a2 * b1; cacc[2][2] += a2 * b2; cacc[2][3] += a2 * b3;
        cacc[3][0] += a3 * b0; cacc[3][1] += a3 * b1; cacc[3][2] += a3 * b2; cacc[3][3] += a3 * b3;
      }
      __syncthreads();
    }
#pragma unroll
    for (int j = 0; j < 4; ++j) {
      int col = m0 + (tx << 2) + j;
#pragma unroll
      for (int i = 0; i < 4; ++i) {
        float v = cacc[i][j];
        if (v > bestv[i]) { bestv[i] = v; besti[i] = col; }
      }
    }
  }
#pragma unroll
  for (int i = 0; i < 4; ++i) { rv[(ty << 2) + i][tx] = bestv[i]; ri[(ty << 2) + i][tx] = besti[i]; }
  __syncthreads();
  if (tid < 64) {
    float bv = rv[tid][0]; int bi = ri[tid][0];
#pragma unroll
    for (int t2 = 1; t2 < 16; ++t2) {
      float v = rv[tid][t2]; int ii = ri[tid][t2];
      if (v > bv || (v == bv && ii < bi)) { bv = v; bi = ii; }
    }
    wv[(b << 12) + n0 + tid] = bv;
    idxv[(b << 12) + n0 + tid] = bi;
  }
}

// ---------------- K_epi: attmap upsample (bid<1024) + gated hybrid conv (bid>=1024) ----------------
__global__ __launch_bounds__(256) void k_epi(const int* __restrict__ mark, float* __restrict__ att,
                                             const float* __restrict__ x, const float* __restrict__ mask,
                                             const float* __restrict__ partMax,
                                             const float* __restrict__ fq, const float* __restrict__ fs,
                                             const float* __restrict__ Wc, const float* __restrict__ bc,
                                             const int* __restrict__ idxv, const float* __restrict__ wv,
                                             float* __restrict__ out) {
  int bid = blockIdx.x;
  int tid = threadIdx.x;
  if (bid < 1024) {
    int id = bid * 256 + tid;
    int x8 = (id & 63) << 3;
    int y = (id >> 6) & 511;
    int b = id >> 15;
    float v = mark[((y >> 3) << 6) + (x8 >> 3)] ? 1.f : 0.f;
    float4 vv = make_float4(v, v, v, v);
    float* p = att + (((size_t)b) << 18) + (y << 9) + x8;
    *reinterpret_cast<float4*>(p) = vv;
    *reinterpret_cast<float4*>(p + 4) = vv;
    return;
  }
  // ---- gated 1x1-conv hybrid overwrite (inline valid + softmax scalars) ----
  int rr = bid - 1024;      // 0..127
  int b = rr >> 4;
  int bx = rr & 15;
  float fore = block_fore(partMax, b);
  if (!(fore > 0.5f) || mask[b << 12] == 0.f) return;  // valid==0
  __shared__ float red[256];
  float mx = -INFINITY;
  for (int n = tid; n < N_; n += 256) mx = fmaxf(mx, wv[(b << 12) + n]);
  red[tid] = mx; __syncthreads();
  for (int s = 128; s; s >>= 1) { if (tid < s) red[tid] = fmaxf(red[tid], red[tid + s]); __syncthreads(); }
  mx = red[0]; __syncthreads();
  float sm = 0.f;
  for (int n = tid; n < N_; n += 256) sm += expf(wv[(b << 12) + n] - mx);
  red[tid] = sm; __syncthreads();
  for (int s = 128; s; s >>= 1) { if (tid < s) red[tid] += red[tid + s]; __syncthreads(); }
  float den = red[0];

  int n = bx * 256 + tid;
  int bn = (b << 12) + n;
  float mn = mask[bn];
  if (mn == 0.f) return;
  int j = idxv[bn];
  float w = expf(wv[bn] - mx) / den;
  float fsj = fs[(b << 12) + j];
  float fqn = fq[bn];
  const float* xb = x + (((size_t)b * C_) << 12);
  for (int o = 0; o < C_; ++o) {
    const float* wr = Wc + o * 2 * C_;
    float a1 = 0.f, a2 = 0.f;
    for (int i = 0; i < C_; ++i) {
      a1 += wr[i] * xb[((size_t)i << 12) + j];
      a2 += wr[C_ + i] * xb[((size_t)i << 12) + n];
    }
    out[((size_t)(b * C_ + o) << 12) + n] = bc[o] + a1 * (fsj * w) + a2 * fqn;
  }
}

extern "C" void kernel_launch(void* const* d_in, const int* in_sizes, int n_in,
                              void* d_out, int out_size, void* d_ws, size_t ws_size,
                              hipStream_t stream) {
  const float* x = (const float*)d_in[0];
  const float* mask = (const float*)d_in[1];
  const float* Wc = (const float*)d_in[2];
  const float* bc = (const float*)d_in[3];
  float* out = (float*)d_out;
  float* att = out + (size_t)B_ * C_ * N_;

  float* wsf = (float*)d_ws;
  float* fq = wsf;                          // 32768
  float* fs = wsf + 32768;                  // 32768
  float* wv = wsf + 65536;                  // 32768
  int* idxv = (int*)(wsf + 98304);          // 32768 -> ends 131072
  int* rowsrc = (int*)(wsf + 131072);       // 4096
  int* rowrank = (int*)(wsf + 135168);      // 4096
  int* colsrc = (int*)(wsf + 139264);       // 4096
  int* colmapG = (int*)(wsf + 143360);      // 4096
  int* cnt = (int*)(wsf + 147456);          // 8 -> ends 147464
  int* mark = (int*)(wsf + 655392);         // 4096 -> ends 659488
  float* partMax = wsf + 659488;            // 512 -> ends 660000
  float* p7V = wsf + 660000;                // 131072 -> ends 791072
  int* p7I = (int*)(wsf + 791072);          // 131072 -> ends 922144
  unsigned short* qhi = (unsigned short*)(wsf + 922144);   // 524288 floats (2MB) each
  unsigned short* qlo = (unsigned short*)(wsf + 1446432);
  unsigned short* shi = (unsigned short*)(wsf + 1970720);
  unsigned short* slo = (unsigned short*)(wsf + 2495008);  // end: 3019296 floats (~11.5MB)

  k_base<<<dim3(64, B_ + 1), 512, 0, stream>>>(x, mask, fq, fs, out, partMax, mark,
                                               qhi, qlo, shi, slo,
                                               rowsrc, rowrank, colsrc, colmapG, cnt);
  k_sim7<<<1024, 256, 0, stream>>>(qhi, qlo, shi, slo, rowsrc, colsrc, colmapG, cnt, p7V, p7I);
  k_mid<<<464, 256, 0, stream>>>(x, mask, partMax, fq, fs, p7V, p7I, rowrank, cnt, wv, idxv, mark);
  k_epi<<<1152, 256, 0, stream>>>(mark, att, x, mask, partMax, fq, fs, Wc, bc, idxv, wv, out);
}

// Round 14
// 62.117 us; speedup vs baseline: 3.8959x; 1.0042x over previous
//
#include <hip/hip_runtime.h>
#include <cmath>

#define B_ 8
#define C_ 256
#define N_ 4096
#define EPS_ 1e-8f

typedef _Float16 half8 __attribute__((ext_vector_type(8)));
typedef float f32x4 __attribute__((ext_vector_type(4)));
typedef unsigned short ushort8 __attribute__((ext_vector_type(8)));

__device__ __forceinline__ void gload_lds16(const void* g, void* l) {
  __builtin_amdgcn_global_load_lds((const __attribute__((address_space(1))) unsigned int*)g,
                                   (__attribute__((address_space(3))) unsigned int*)l, 16, 0, 0);
}

// Block-uniform need/valid recompute from partMax (64 partials per batch).
__device__ __forceinline__ float block_fore(const float* __restrict__ partMax, int b) {
  int l = threadIdx.x & 63;
  float v = partMax[(b << 6) + l];
#pragma unroll
  for (int d = 32; d; d >>= 1) v = fmaxf(v, __shfl_xor(v, d, 64));
  return v;
}

// ---------------- K_base: fused norms + valid-partial + base out + b=7 fp16 prep + cmp7 (b==8 row) ----
__global__ __launch_bounds__(512) void k_base(const float* __restrict__ x, const float* __restrict__ mask,
                                              float* __restrict__ fq, float* __restrict__ fs,
                                              float* __restrict__ out, float* __restrict__ partMax,
                                              int* __restrict__ mark,
                                              unsigned short* __restrict__ qhi, unsigned short* __restrict__ qlo,
                                              unsigned short* __restrict__ shi, unsigned short* __restrict__ slo,
                                              int* __restrict__ rowsrc, int* __restrict__ rowrank,
                                              int* __restrict__ colsrc, int* __restrict__ colmapG,
                                              int* __restrict__ cnt) {
  int b = blockIdx.y, n0 = blockIdx.x << 6;
  int t = threadIdx.x;            // 0..511
  if (b == B_) {
    // ---- compaction scan for b=7 (1 block of 512 threads, 8 elements each; stable order) ----
    if (blockIdx.x != 0) return;
    __shared__ int wtot[8], wbase[8], stot_s;
    int n0c = t << 3;
#pragma unroll
    for (int i = 0; i < 8; ++i) {
      rowsrc[t + (i << 9)] = 0;
      colsrc[t + (i << 9)] = 0;
      colmapG[t + (i << 9)] = 0x3fffffff;  // tail slots: huge but monotone col index
    }
    __syncthreads();
    int f[8]; int pk = 0;
#pragma unroll
    for (int i = 0; i < 8; ++i) {
      int m = (mask[(7 << 12) + n0c + i] != 0.f) ? 1 : 0;
      f[i] = m;
      pk += m ? 1 : (1 << 16);  // low 16: rows (m=1), high 16: cols (m=0)
    }
    int incl = pk;
#pragma unroll
    for (int d = 1; d < 64; d <<= 1) {
      int o = __shfl_up(incl, d, 64);
      if ((t & 63) >= d) incl += o;
    }
    if ((t & 63) == 63) wtot[t >> 6] = incl;
    __syncthreads();
    if (t < 8) {
      int s2 = 0;
      for (int i = 0; i < t; ++i) s2 += wtot[i];
      wbase[t] = s2;
      if (t == 7) stot_s = s2 + wtot[7];
    }
    __syncthreads();
    int excl = wbase[t >> 6] + incl - pk;   // packed exclusive prefix
    int rslot = excl & 0xffff, cslot = excl >> 16;
#pragma unroll
    for (int i = 0; i < 8; ++i) {
      int n2 = n0c + i;
      if (f[i]) { rowsrc[rslot] = n2; rowrank[n2] = rslot; ++rslot; }
      else      { rowrank[n2] = -1; colsrc[cslot] = n2; colmapG[cslot] = n2; ++cslot; }
    }
    __syncthreads();
    if (t == 0) {
      int tot = stot_s;
      int nr = tot & 0xffff;
      cnt[0] = nr;
      cnt[1] = tot >> 16;
      cnt[2] = (nr > 0) ? rowsrc[0] : 0x7fffffff;  // j0 = first inactive support col
    }
    return;
  }
  int ln = t & 63, cg = t >> 6;   // 8 groups x 32 channels
  __shared__ float sred[512];
  __shared__ float s0[256];
  __shared__ float rss[8][64], rdp[8][64];
  __shared__ float scaleS[64], f64q[64], f64s[64];
  __shared__ float bcast[2];
  if (b == 0 && blockIdx.x == 0) {
#pragma unroll
    for (int i = 0; i < 8; ++i) mark[t + (i << 9)] = 0;
  }
  const size_t xbase = ((size_t)b * C_) << 12;
  float xc0 = 0.f;
  if (t < 256) xc0 = x[xbase + ((size_t)t << 12)];
  sred[t] = xc0 * xc0;
  __syncthreads();
  for (int s = 256; s; s >>= 1) { if (t < s) sred[t] += sred[t + s]; __syncthreads(); }
  if (t == 0) { bcast[0] = 1.f / (sqrtf(sred[0]) + EPS_); bcast[1] = mask[b << 12]; }
  __syncthreads();
  if (t < 256) s0[t] = xc0 * ((1.f - bcast[1]) * bcast[0]);
  __syncthreads();
  int n = n0 + ln;
  const float* xp = x + xbase + (((size_t)cg) << 17) + n;
  float xv[32];
  float ss = 0.f, dp = 0.f;
#pragma unroll
  for (int c = 0; c < 32; ++c) {
    float v = xp[(size_t)c << 12];
    xv[c] = v;
    ss += v * v;
    dp += v * s0[(cg << 5) + c];
  }
  rss[cg][ln] = ss; rdp[cg][ln] = dp;
  __syncthreads();
  if (t < 64) {
    float sst = 0.f, dpt = 0.f;
#pragma unroll
    for (int g = 0; g < 8; ++g) { sst += rss[g][t]; dpt += rdp[g][t]; }
    float inv = 1.f / (sqrtf(sst) + EPS_);
    float m = mask[(b << 12) + n0 + t];
    float fqv = m * inv;
    fq[(b << 12) + n0 + t] = fqv;
    fs[(b << 12) + n0 + t] = (1.f - m) * inv;
    scaleS[t] = (m != 0.f) ? inv : 1.f;
    f64q[t] = fqv * 64.0f;
    f64s[t] = (1.f - m) * inv * 64.0f;
    float val = dpt * fqv;  // masked rows -> exactly 0
#pragma unroll
    for (int d = 32; d; d >>= 1) val = fmaxf(val, __shfl_xor(val, d, 64));
    if (t == 0) partMax[(b << 6) + blockIdx.x] = val;
  }
  __syncthreads();
  float sc = scaleS[ln];
  float* op = out + xbase + (((size_t)cg) << 17) + n;
#pragma unroll
  for (int c = 0; c < 32; ++c) op[(size_t)c << 12] = xv[c] * sc;
  if (b == B_ - 1) {
    // fused prep: scaled (x64) fp16 hi/lo split, transposed, LINEAR layout (swizzle at staging)
    float fqn = f64q[ln], fsn = f64s[ln];
    size_t rowbase = ((size_t)n) << 8;  // 256 shorts per row
#pragma unroll
    for (int j = 0; j < 4; ++j) {
      ushort8 vqh, vql, vsh, vsl;
#pragma unroll
      for (int i = 0; i < 8; ++i) {
        float xvv = xv[j * 8 + i];
        float qv = xvv * fqn;
        _Float16 qh = (_Float16)qv;
        _Float16 ql = (_Float16)((qv - (float)qh) * 2048.0f);
        float sv = xvv * fsn;
        _Float16 sh = (_Float16)sv;
        _Float16 sl = (_Float16)((sv - (float)sh) * 2048.0f);
        vqh[i] = __builtin_bit_cast(unsigned short, qh);
        vql[i] = __builtin_bit_cast(unsigned short, ql);
        vsh[i] = __builtin_bit_cast(unsigned short, sh);
        vsl[i] = __builtin_bit_cast(unsigned short, sl);
      }
      size_t off = rowbase + ((size_t)cg << 5) + ((size_t)j << 3);
      *reinterpret_cast<ushort8*>(qhi + off) = vqh;
      *reinterpret_cast<ushort8*>(qlo + off) = vql;
      *reinterpret_cast<ushort8*>(shi + off) = vsh;
      *reinterpret_cast<ushort8*>(slo + off) = vsl;
    }
  }
}

// ---------------- K_sim7: compacted MFMA sim, 8 waves/block (r12-verified body, fence-free) -------
__global__ __launch_bounds__(512, 2) void k_sim7(const unsigned short* __restrict__ qhi, const unsigned short* __restrict__ qlo,
                                                 const unsigned short* __restrict__ shi, const unsigned short* __restrict__ slo,
                                                 const int* __restrict__ rowsrc, const int* __restrict__ colsrc,
                                                 const int* __restrict__ colmapG, const int* __restrict__ cnt,
                                                 float* __restrict__ partV, int* __restrict__ partI) {
  int nrows = cnt[0], ncols = cnt[1];
  int bid = blockIdx.x;
  int mt = bid & 31, nt = bid >> 5;
  if ((nt << 7) >= nrows || (mt << 7) >= ncols) return;  // data-dependent tile cull
  int tid = threadIdx.x;
  int w = tid >> 6, lane = tid & 63;
  int wy = w >> 2, wx = w & 3;           // 2 row-halves x 4 col-quarters
  int arr = w >> 1, shalf = w & 1;       // staging: array 0..3, seg half
  __shared__ __align__(16) unsigned short smem[2][16384];  // 2 x 32KB double buffer

  f32x4 acc_h[4][2], acc_c[4][2];
#pragma unroll
  for (int i = 0; i < 4; ++i)
#pragma unroll
    for (int j = 0; j < 2; ++j) {
      acc_h[i][j] = (f32x4){0.f, 0.f, 0.f, 0.f};
      acc_c[i][j] = (f32x4){0.f, 0.f, 0.f, 0.f};
    }

  const unsigned short* gsrc = (arr == 0) ? qhi : (arr == 1) ? qlo : (arr == 2) ? shi : slo;
  const int* srcmap = (arr < 2) ? rowsrc : colsrc;
  int n0 = ((arr < 2) ? nt : mt) << 7;
  int lrow = lane >> 2, lch = lane & 3;
  int chx = (lch ^ ((lrow >> 1) & 3)) << 3;   // slot-keyed chunk swizzle
  int s = lane >> 4, c16 = lane & 15;
  int srco[4];
#pragma unroll
  for (int s2 = 0; s2 < 4; ++s2) {
    int seg = (shalf << 2) + s2;
    srco[s2] = (srcmap[n0 + (seg << 4) + lrow] << 8) + chx;
  }

#define STAGE7(buf, kt)                                                                   \
  _Pragma("unroll")                                                                       \
  for (int s2 = 0; s2 < 4; ++s2) {                                                        \
    const unsigned short* g = gsrc + (size_t)(srco[s2] + ((kt) << 5));                    \
    gload_lds16(g, &smem[buf][(arr << 12) + ((((shalf << 2) + s2)) << 9)]);               \
  }

  STAGE7(0, 0);

  int cur = 0;
  for (int kt = 0; kt < 8; ++kt) {
    if (kt < 7) {
      STAGE7(cur ^ 1, kt + 1);
      asm volatile("s_waitcnt vmcnt(4)" ::: "memory");   // own cur-buffer loads retired
    } else {
      asm volatile("s_waitcnt vmcnt(0)" ::: "memory");
    }
    __builtin_amdgcn_s_barrier();
    __builtin_amdgcn_sched_barrier(0);
    const unsigned short* sm = &smem[cur][0];
    half8 ah[4], al[4], bh[2], bl[2];
#pragma unroll
    for (int f = 0; f < 4; ++f) {
      int ra = (wy << 6) + (f << 4) + c16;
      int oa = ra * 32 + ((s ^ ((ra >> 1) & 3)) << 3);
      ah[f] = *reinterpret_cast<const half8*>(&sm[oa]);
      al[f] = *reinterpret_cast<const half8*>(&sm[4096 + oa]);
    }
#pragma unroll
    for (int f = 0; f < 2; ++f) {
      int rb = (wx << 5) + (f << 4) + c16;
      int ob = rb * 32 + ((s ^ ((rb >> 1) & 3)) << 3);
      bh[f] = *reinterpret_cast<const half8*>(&sm[8192 + ob]);
      bl[f] = *reinterpret_cast<const half8*>(&sm[12288 + ob]);
    }
#pragma unroll
    for (int fi = 0; fi < 4; ++fi)
#pragma unroll
      for (int fj = 0; fj < 2; ++fj) {
        acc_h[fi][fj] = __builtin_amdgcn_mfma_f32_16x16x32_f16(ah[fi], bh[fj], acc_h[fi][fj], 0, 0, 0);
        acc_c[fi][fj] = __builtin_amdgcn_mfma_f32_16x16x32_f16(ah[fi], bl[fj], acc_c[fi][fj], 0, 0, 0);
        acc_c[fi][fj] = __builtin_amdgcn_mfma_f32_16x16x32_f16(al[fi], bh[fj], acc_c[fi][fj], 0, 0, 0);
      }
    asm volatile("s_waitcnt lgkmcnt(0)" ::: "memory");
    __builtin_amdgcn_s_barrier();
    __builtin_amdgcn_sched_barrier(0);
    cur ^= 1;
  }
#undef STAGE7
  int cg4[2], cok[2];
#pragma unroll
  for (int fj = 0; fj < 2; ++fj) {
    int slotg = (mt << 7) + (wx << 5) + (fj << 4) + c16;
    cg4[fj] = colmapG[slotg];
    cok[fj] = slotg < ncols;
  }
  float* redV = reinterpret_cast<float*>(&smem[0][0]);       // [128][4]
  int* redI = reinterpret_cast<int*>(&smem[0][1024]);        // [128][4]
  int g16 = lane >> 4;
#pragma unroll
  for (int fi = 0; fi < 4; ++fi)
#pragma unroll
    for (int r2 = 0; r2 < 4; ++r2) {
      float bv = -INFINITY; int bi = 0x7fffffff;
#pragma unroll
      for (int fj = 0; fj < 2; ++fj) {
        float v = cok[fj] ? (acc_h[fi][fj][r2] + acc_c[fi][fj][r2] * (1.0f / 2048.0f)) * (1.0f / 4096.0f)
                          : -INFINITY;
        int colg = cg4[fj];
        if (v > bv) { bv = v; bi = colg; }
      }
#pragma unroll
      for (int d = 1; d < 16; d <<= 1) {
        float ov = __shfl_xor(bv, d, 64);
        int oi = __shfl_xor(bi, d, 64);
        if (ov > bv || (ov == bv && oi < bi)) { bv = ov; bi = oi; }
      }
      if (c16 == 0) {
        int row = (wy << 6) + (fi << 4) + (g16 << 2) + r2;
        redV[row * 4 + wx] = bv;
        redI[row * 4 + wx] = bi;
      }
    }
  __syncthreads();
  if (tid < 128) {
    float bv = redV[tid * 4]; int bi = redI[tid * 4];
#pragma unroll
    for (int q = 1; q < 4; ++q) {   // wx ascending -> cols ascending
      float v = redV[tid * 4 + q]; int i = redI[tid * 4 + q];
      if (v > bv || (v == bv && i < bi)) { bv = v; bi = i; }
    }
    int n = (nt << 7) + tid;   // compact slot row
    partV[(((size_t)n) << 5) + mt] = bv;
    partI[(((size_t)n) << 5) + mt] = bi;
  }
}

// ---------------- K_mid: red7m (bid<16) + legacy simL (bid>=16, gated ~never runs) ----------------
__global__ __launch_bounds__(256) void k_mid(const float* __restrict__ x, const float* __restrict__ mask,
                                             const float* __restrict__ partMax,
                                             const float* __restrict__ fq, const float* __restrict__ fs,
                                             const float* __restrict__ p7V, const int* __restrict__ p7I,
                                             const int* __restrict__ rowrank, const int* __restrict__ cnt,
                                             float* __restrict__ wv, int* __restrict__ idxv,
                                             int* __restrict__ mark) {
  int bid = blockIdx.x;
  int tid = threadIdx.x;
  if (bid < 16) {
    // ---- de-compact reduce for b=7 + inactive-col candidate + mark ----
    int n = bid * 256 + tid;   // orig row
    int ncols = cnt[1], j0 = cnt[2];
    int rk = rowrank[n];
    float bv; int bi;
    if (rk < 0) {
      bv = 0.f; bi = 0;
    } else {
      bv = -INFINITY; bi = 0x7fffffff;
      int mtmax = (ncols + 127) >> 7;
      for (int mt = 0; mt < mtmax; ++mt) {
        float v = p7V[(((size_t)rk) << 5) + mt];
        int i = p7I[(((size_t)rk) << 5) + mt];
        if (v > bv || (v == bv && i < bi)) { bv = v; bi = i; }
      }
      if (j0 < N_) {
        if (0.f > bv) { bv = 0.f; bi = j0; }
        else if (0.f == bv && j0 < bi) bi = j0;
      }
    }
    wv[((B_ - 1) << 12) + n] = bv;
    idxv[((B_ - 1) << 12) + n] = bi;
    mark[bi] = 1;  // benign same-value race
    return;
  }
  // ---- legacy fp32 sim for b<7, full-row argmax ----
  int rr = bid - 16;
  int b = rr >> 6;
  float fore = block_fore(partMax, b);
  if (!(fore > 0.5f) || mask[b << 12] == 0.f) return;  // need==0 for b<7
  int n0 = (rr & 63) << 6;
  int tx = tid & 15, ty = tid >> 4;
  int lk = ty, ln4 = tx << 2;

  __shared__ float As[16][68];
  __shared__ float Bs[16][68];
  __shared__ float fqs[64], fss[64];
  __shared__ float rv[64][17];
  __shared__ int ri[64][17];

  if (tid < 64) fqs[tid] = fq[(b << 12) + n0 + tid];

  float bestv[4]; int besti[4];
#pragma unroll
  for (int i = 0; i < 4; ++i) { bestv[i] = -INFINITY; besti[i] = 0; }

  const size_t xb = ((size_t)b * C_) << 12;

  for (int m0 = 0; m0 < N_; m0 += 64) {
    if (tid < 64) fss[tid] = fs[(b << 12) + m0 + tid];
    float cacc[4][4];
#pragma unroll
    for (int i = 0; i < 4; ++i)
#pragma unroll
      for (int j = 0; j < 4; ++j) cacc[i][j] = 0.f;
    __syncthreads();
    for (int kt = 0; kt < C_; kt += 16) {
      float4 va = *reinterpret_cast<const float4*>(x + xb + ((size_t)(kt + lk) << 12) + n0 + ln4);
      float4 vb = *reinterpret_cast<const float4*>(x + xb + ((size_t)(kt + lk) << 12) + m0 + ln4);
      va.x *= fqs[ln4]; va.y *= fqs[ln4 + 1]; va.z *= fqs[ln4 + 2]; va.w *= fqs[ln4 + 3];
      vb.x *= fss[ln4]; vb.y *= fss[ln4 + 1]; vb.z *= fss[ln4 + 2]; vb.w *= fss[ln4 + 3];
      *reinterpret_cast<float4*>(&As[lk][ln4]) = va;
      *reinterpret_cast<float4*>(&Bs[lk][ln4]) = vb;
      __syncthreads();
#pragma unroll
      for (int k = 0; k < 16; ++k) {
        float a0 = As[k][(ty << 2) + 0], a1 = As[k][(ty << 2) + 1], a2 = As[k][(ty << 2) + 2], a3 = As[k][(ty << 2) + 3];
        float b0 = Bs[k][(tx << 2) + 0], b1 = Bs[k][(tx << 2) + 1], b2 = Bs[k][(tx << 2) + 2], b3 = Bs[k][(tx << 2) + 3];
        cacc[0][0] += a0 * b0; cacc[0][1] += a0 * b1; cacc[0][2] += a0 * b2; cacc[0][3] += a0 * b3;
        cacc[1][0] += a1 * b0; cacc[1][1] += a1 * b1; cacc[1][2] += a1 * b2; cacc[1][3] += a1 * b3;
        cacc[2][0] += a2 * b0; cacc[2][1] += a2 * b1; cacc[2][2] += a2 * b2; cacc[2][3] += a2 * b3;
        cacc[3][0] += a3 * b0; cacc[3][1] += a3 * b1; cacc[3][2] += a3 * b2; cacc[3][3] += a3 * b3;
      }
      __syncthreads();
    }
#pragma unroll
    for (int j = 0; j < 4; ++j) {
      int col = m0 + (tx << 2) + j;
#pragma unroll
      for (int i = 0; i < 4; ++i) {
        float v = cacc[i][j];
        if (v > bestv[i]) { bestv[i] = v; besti[i] = col; }
      }
    }
  }
#pragma unroll
  for (int i = 0; i < 4; ++i) { rv[(ty << 2) + i][tx] = bestv[i]; ri[(ty << 2) + i][tx] = besti[i]; }
  __syncthreads();
  if (tid < 64) {
    float bv = rv[tid][0]; int bi = ri[tid][0];
#pragma unroll
    for (int t2 = 1; t2 < 16; ++t2) {
      float v = rv[tid][t2]; int ii = ri[tid][t2];
      if (v > bv || (v == bv && ii < bi)) { bv = v; bi = ii; }
    }
    wv[(b << 12) + n0 + tid] = bv;
    idxv[(b << 12) + n0 + tid] = bi;
  }
}

// ---------------- K_epi: attmap upsample (bid<1024) + gated hybrid conv (bid>=1024) ----------------
__global__ __launch_bounds__(256) void k_epi(const int* __restrict__ mark, float* __restrict__ att,
                                             const float* __restrict__ x, const float* __restrict__ mask,
                                             const float* __restrict__ partMax,
                                             const float* __restrict__ fq, const float* __restrict__ fs,
                                             const float* __restrict__ Wc, const float* __restrict__ bc,
                                             const int* __restrict__ idxv, const float* __restrict__ wv,
                                             float* __restrict__ out) {
  int bid = blockIdx.x;
  int tid = threadIdx.x;
  if (bid < 1024) {
    int id = bid * 256 + tid;
    int x8 = (id & 63) << 3;
    int y = (id >> 6) & 511;
    int b = id >> 15;
    float v = mark[((y >> 3) << 6) + (x8 >> 3)] ? 1.f : 0.f;
    float4 vv = make_float4(v, v, v, v);
    float* p = att + (((size_t)b) << 18) + (y << 9) + x8;
    *reinterpret_cast<float4*>(p) = vv;
    *reinterpret_cast<float4*>(p + 4) = vv;
    return;
  }
  // ---- gated 1x1-conv hybrid overwrite (inline valid + softmax scalars) ----
  int rr = bid - 1024;      // 0..127
  int b = rr >> 4;
  int bx = rr & 15;
  float fore = block_fore(partMax, b);
  if (!(fore > 0.5f) || mask[b << 12] == 0.f) return;  // valid==0
  __shared__ float red[256];
  float mx = -INFINITY;
  for (int n = tid; n < N_; n += 256) mx = fmaxf(mx, wv[(b << 12) + n]);
  red[tid] = mx; __syncthreads();
  for (int s = 128; s; s >>= 1) { if (tid < s) red[tid] = fmaxf(red[tid], red[tid + s]); __syncthreads(); }
  mx = red[0]; __syncthreads();
  float sm = 0.f;
  for (int n = tid; n < N_; n += 256) sm += expf(wv[(b << 12) + n] - mx);
  red[tid] = sm; __syncthreads();
  for (int s = 128; s; s >>= 1) { if (tid < s) red[tid] += red[tid + s]; __syncthreads(); }
  float den = red[0];

  int n = bx * 256 + tid;
  int bn = (b << 12) + n;
  float mn = mask[bn];
  if (mn == 0.f) return;
  int j = idxv[bn];
  float w = expf(wv[bn] - mx) / den;
  float fsj = fs[(b << 12) + j];
  float fqn = fq[bn];
  const float* xb = x + (((size_t)b * C_) << 12);
  for (int o = 0; o < C_; ++o) {
    const float* wr = Wc + o * 2 * C_;
    float a1 = 0.f, a2 = 0.f;
    for (int i = 0; i < C_; ++i) {
      a1 += wr[i] * xb[((size_t)i << 12) + j];
      a2 += wr[C_ + i] * xb[((size_t)i << 12) + n];
    }
    out[((size_t)(b * C_ + o) << 12) + n] = bc[o] + a1 * (fsj * w) + a2 * fqn;
  }
}

extern "C" void kernel_launch(void* const* d_in, const int* in_sizes, int n_in,
                              void* d_out, int out_size, void* d_ws, size_t ws_size,
                              hipStream_t stream) {
  const float* x = (const float*)d_in[0];
  const float* mask = (const float*)d_in[1];
  const float* Wc = (const float*)d_in[2];
  const float* bc = (const float*)d_in[3];
  float* out = (float*)d_out;
  float* att = out + (size_t)B_ * C_ * N_;

  float* wsf = (float*)d_ws;
  float* fq = wsf;                          // 32768
  float* fs = wsf + 32768;                  // 32768
  float* wv = wsf + 65536;                  // 32768
  int* idxv = (int*)(wsf + 98304);          // 32768 -> ends 131072
  int* rowsrc = (int*)(wsf + 131072);       // 4096
  int* rowrank = (int*)(wsf + 135168);      // 4096
  int* colsrc = (int*)(wsf + 139264);       // 4096
  int* colmapG = (int*)(wsf + 143360);      // 4096
  int* cnt = (int*)(wsf + 147456);          // 8 -> ends 147464
  int* mark = (int*)(wsf + 655392);         // 4096 -> ends 659488
  float* partMax = wsf + 659488;            // 512 -> ends 660000
  float* p7V = wsf + 660000;                // 131072 -> ends 791072
  int* p7I = (int*)(wsf + 791072);          // 131072 -> ends 922144
  unsigned short* qhi = (unsigned short*)(wsf + 922144);   // 524288 floats (2MB) each
  unsigned short* qlo = (unsigned short*)(wsf + 1446432);
  unsigned short* shi = (unsigned short*)(wsf + 1970720);
  unsigned short* slo = (unsigned short*)(wsf + 2495008);  // end: 3019296 floats (~11.5MB)

  k_base<<<dim3(64, B_ + 1), 512, 0, stream>>>(x, mask, fq, fs, out, partMax, mark,
                                               qhi, qlo, shi, slo,
                                               rowsrc, rowrank, colsrc, colmapG, cnt);
  k_sim7<<<1024, 512, 0, stream>>>(qhi, qlo, shi, slo, rowsrc, colsrc, colmapG, cnt, p7V, p7I);
  k_mid<<<464, 256, 0, stream>>>(x, mask, partMax, fq, fs, p7V, p7I, rowrank, cnt, wv, idxv, mark);
  k_epi<<<1152, 256, 0, stream>>>(mark, att, x, mask, partMax, fq, fs, Wc, bc, idxv, wv, out);
}